// Round 5
// baseline (133.114 us; speedup 1.0000x reference)
//
#include <hip/hip_runtime.h>

// Problem: x[2048][32][2] fp32 -> pe[2048][32][512] fp32
//   pe[i,b,2p]   = sin(x[i,b,0] * exp(p * -ln(1e4)/256))
//   pe[i,b,2p+1] = cos(x[i,b,1] * exp(p * -ln(1e4)/256))
//
// Write-BW-bound: 134 MB out, 0.5 MB in.
// R3 analysis: dur_us includes ~107 us of harness poison fills (536+134 MB);
// kernel itself ~24.7 us (5.4 TB/s). Gap vs fills' 6.4 TB/s: store-pipeline
// startup (load+trans prologue before first store, only 4 KB stores/wave).
// R5: 16 rows/block -> 8 KB stores/wave, all xy loads hoisted up front.
// (R4 failed to compile: __exp2f is not a device builtin — use exp2f.)

#define NUM_ROWS   (2048 * 32)        // (i,b) pairs
#define V4_PER_ROW (512 / 4)          // 128 float4 per row
#define ROWS_PER_BLOCK 16             // 2048 float4 per block, 8 stores/thread
#define ITERS 8                       // rows per thread

typedef float fvec4 __attribute__((ext_vector_type(4)));

__global__ __launch_bounds__(256) void pe2d_kernel(const float* __restrict__ x,
                                                   float* __restrict__ out) {
    const int tid  = threadIdx.x;
    const int t    = tid & 127;            // float4 index within a row (fixed channel)
    const int r    = tid >> 7;             // 0/1: row offset within pair
    const int row0 = blockIdx.x * ROWS_PER_BLOCK + r;

    // div_term for this thread's channel pair — computed once, reused 8 rows.
    const int   p0 = t * 2;
    const float k  = -0.051905126482615036f;  // -log2(10000)/256
    const float d0 = exp2f(k * (float)p0);
    const float d1 = exp2f(k * (float)(p0 + 1));

    const float2* __restrict__ xv = (const float2*)x;
    fvec4* __restrict__ ov = (fvec4*)out;

    // Hoist all broadcast coord loads: one latency wait, 8 in flight.
    float2 xy[ITERS];
    #pragma unroll
    for (int j = 0; j < ITERS; ++j)
        xy[j] = xv[row0 + 2 * j];

    #pragma unroll
    for (int j = 0; j < ITERS; ++j) {
        fvec4 o;
        o.x = __sinf(xy[j].x * d0);
        o.y = __cosf(xy[j].y * d0);
        o.z = __sinf(xy[j].x * d1);
        o.w = __cosf(xy[j].y * d1);
        ov[(row0 + 2 * j) * V4_PER_ROW + t] = o;   // contiguous 1 KB per wave
    }
}

extern "C" void kernel_launch(void* const* d_in, const int* in_sizes, int n_in,
                              void* d_out, int out_size, void* d_ws, size_t ws_size,
                              hipStream_t stream) {
    const float* x = (const float*)d_in[0];
    float* out = (float*)d_out;
    const int blocks = NUM_ROWS / ROWS_PER_BLOCK;   // 4096
    pe2d_kernel<<<blocks, 256, 0, stream>>>(x, out);
}